// Round 12
// baseline (1207.798 us; speedup 1.0000x reference)
//
#include <hip/hip_runtime.h>
#include <hip/hip_cooperative_groups.h>
#include <hip/hip_bf16.h>
#include <math.h>

namespace cg = cooperative_groups;

typedef __hip_bfloat16 bf16;
typedef __bf16 bf16x8 __attribute__((ext_vector_type(8)));
typedef float f32x4 __attribute__((ext_vector_type(4)));

static constexpr int  B_  = 4, S_ = 2048, H_ = 1024;
static constexpr long BSH = (long)B_ * S_ * H_;   // 8,388,608
static constexpr long SH  = (long)S_ * H_;        // 2,097,152
static constexpr long SS  = (long)S_ * S_;        // 4,194,304
static constexpr long HH  = (long)H_ * H_;        // 1,048,576

// async global->LDS, 16B per lane; LDS dest is wave-uniform base + lane*16
#define GLOAD_LDS16(gp, lp)                                                          \
  __builtin_amdgcn_global_load_lds((__attribute__((address_space(1))) void*)(gp),    \
                                   (__attribute__((address_space(3))) void*)(lp),    \
                                   16, 0, 0)

// raw barrier (does NOT drain vmcnt) + compiler memory fence
#define BARRIER() do { __builtin_amdgcn_s_barrier(); asm volatile("" ::: "memory"); } while (0)

template <int N> __device__ __forceinline__ void waitcnt_vm() {
  if constexpr (N == 0)      asm volatile("s_waitcnt vmcnt(0)" ::: "memory");
  else if constexpr (N == 8) asm volatile("s_waitcnt vmcnt(8)" ::: "memory");
}

__device__ __forceinline__ float wave_reduce_sum(float v) {
#pragma unroll
  for (int o = 32; o; o >>= 1) v += __shfl_xor(v, o, 64);
  return v;
}
__device__ __forceinline__ float bf16r(float v) {
  return __bfloat162float(__float2bfloat16(v));
}

// ================= shared device cores (used by mega kernel AND fallback) =======

// ---- prep virtual-block: weights (0..4095) + PE-add (4096..20479)
//      + mask bit-pack (20480..22527) + pos_bias->bf16 (22528..26623)
__device__ __forceinline__ void prep_core(
    int bx, const float* Wq, const float* Wk, const float* Wv, const float* Wo,
    bf16* wdst, const float* x, bf16* xpb,
    const int* mask, unsigned* mask_bits, const float* pos_bias, bf16* pbb) {
  const int tid = threadIdx.x;
  if (bx < 4096) {
    const int w = bx >> 10;
    const float* src = (w == 0) ? Wq : (w == 1) ? Wk : (w == 2) ? Wv : Wo;
    bf16* d = wdst + (long)w * HH;
    const int idx = ((bx & 1023) << 8) + tid;
    const float4 f = ((const float4*)src)[idx];
    d[idx * 4 + 0] = __float2bfloat16(f.x);
    d[idx * 4 + 1] = __float2bfloat16(f.y);
    d[idx * 4 + 2] = __float2bfloat16(f.z);
    d[idx * 4 + 3] = __float2bfloat16(f.w);
  } else if (bx < 20480) {
    const long idx = (((long)(bx - 4096)) << 8) + tid;     // over B*S*(H/2)
    const int  i   = (int)(idx & (H_ / 2 - 1));
    const long bs  = idx >> 9;
    const int  s   = (int)(bs & (S_ - 1));
    const float div = __expf((float)(2 * i) * (-9.210340371976184f / (float)H_));
    const float ang = (float)s * div;
    const float2 xv = ((const float2*)x)[idx];
    xpb[idx * 2 + 0] = __float2bfloat16(xv.x + __sinf(ang));
    xpb[idx * 2 + 1] = __float2bfloat16(xv.y + __cosf(ang));
  } else if (bx < 22528) {
    const long uidx = (((long)(bx - 20480)) << 8) + tid;
    const int4* mp  = (const int4*)mask + uidx * 8;
    unsigned bits = 0;
#pragma unroll
    for (int q = 0; q < 8; ++q) {
      const int4 v = mp[q];
      bits |= (v.x ? 1u : 0u) << (q * 4 + 0);
      bits |= (v.y ? 1u : 0u) << (q * 4 + 1);
      bits |= (v.z ? 1u : 0u) << (q * 4 + 2);
      bits |= (v.w ? 1u : 0u) << (q * 4 + 3);
    }
    mask_bits[uidx] = bits;
  } else {
    const long idx = (((long)(bx - 22528)) << 8) + tid;
    const float4 f = ((const float4*)pos_bias)[idx];
    bf16* d = pbb + idx * 4;
    d[0] = __float2bfloat16(f.x);
    d[1] = __float2bfloat16(f.y);
    d[2] = __float2bfloat16(f.z);
    d[3] = __float2bfloat16(f.w);
  }
}

// ---- NT GEMM core, 128x128 tile, BK=64, 256 thr. As/Bs point to NBUF x 16KB.
// DBUF=false: stage -> syncthreads(drain) -> compute -> syncthreads (r6 winner)
// DBUF=true : counted-vmcnt double-buffer (r7; used only in fallback MODE 2)
// Read-side k-slot XOR (row&7) swizzle; inverse perm on GLOBAL source (rule 21).
// MODE 0: Cb = bf16(acc + biasz[col]); z==0 scaled 1/32 (exact exponent shift)
// MODE 1: Cb = bf16(exp(clamp(acc + pbb, maskbit)))   (acc pre-scaled)
// MODE 2: Cb = bf16(acc * inv_sum[z*S+row])
// MODE 3: Cf = acc + bias0[col] + xres[m,n]  (fp32)
// MODE 4: Cb = bf16(acc + bias0[ROW])        (vT = Wv @ xpb^T + bv, H x S out)
template <int MODE, bool DBUF>
__device__ __forceinline__ void gemm_core(
    bf16* As, bf16* Bs, int bxx, int byy, int z,
    const bf16* A, long sA, const bf16* Bm, long sB,
    bf16* Cb, float* Cf, long sC, int M, int N, int K,
    const float* bias0, const float* bias1,
    const bf16* pbb, const unsigned* mask_bits,
    const float* xres, const float* inv_sum) {
  constexpr int BM = 128, BN = 128, BK = 64;
  constexpr int TILE = BM * BK;              // 8192 bf16 = 16KB

  const int tid  = threadIdx.x;
  const int lane = tid & 63;
  const int wave = tid >> 6;
  const int wm   = wave & 1;
  const int wn   = wave >> 1;
  const int m0   = bxx * BM;
  const int n0   = byy * BN;

  const bf16* Ab = A  + (long)z * sA;
  const bf16* Bb = Bm + (long)z * sB;

  const int rw = tid >> 3;                   // base row (rows rw+32q)
  const int cp = (tid & 7) ^ (rw & 7);       // permuted global 16B-colslot
  const bf16* ga = Ab + (long)(m0 + rw) * K + cp * 8;
  const bf16* gb = Bb + (long)(n0 + rw) * K + cp * 8;

  auto stage = [&](int tile, int buf) {
    const long k0 = (long)tile * BK;
#pragma unroll
    for (int q = 0; q < 4; ++q) {
      GLOAD_LDS16(ga + (long)(32 * q) * K + k0, As + buf * TILE + tid * 8 + q * 2048);
      GLOAD_LDS16(gb + (long)(32 * q) * K + k0, Bs + buf * TILE + tid * 8 + q * 2048);
    }
  };

  f32x4 acc[4][4] = {};

  const int fr     = lane & 15;
  const int k0slot = lane >> 4;
  const int sw     = fr & 7;

  auto tile_compute = [&](const char* bAc, const char* bBc) {
#pragma unroll
    for (int ks = 0; ks < 2; ++ks) {
      const int co = ((k0slot + 4 * ks) ^ sw) << 4;
      bf16x8 af[4], bfv[4];
#pragma unroll
      for (int i = 0; i < 4; ++i) {
        af[i]  = *(const bf16x8*)(bAc + (wm * 64 + i * 16 + fr) * 128 + co);
        bfv[i] = *(const bf16x8*)(bBc + (wn * 64 + i * 16 + fr) * 128 + co);
      }
#pragma unroll
      for (int i = 0; i < 4; ++i)
#pragma unroll
        for (int j = 0; j < 4; ++j)
          acc[i][j] = __builtin_amdgcn_mfma_f32_16x16x32_bf16(af[i], bfv[j], acc[i][j], 0, 0, 0);
    }
  };

  const int nkt = K / BK;
  if constexpr (DBUF) {
    stage(0, 0);
    for (int kt = 0; kt < nkt; ++kt) {
      const int cur = kt & 1;
      if (kt + 1 < nkt) {
        stage(kt + 1, cur ^ 1);
        waitcnt_vm<8>();
      } else {
        waitcnt_vm<0>();
      }
      BARRIER();
      tile_compute((const char*)(As + cur * TILE), (const char*)(Bs + cur * TILE));
      BARRIER();
    }
  } else {
    for (int kt = 0; kt < nkt; ++kt) {
      stage(kt, 0);
      __syncthreads();
      tile_compute((const char*)As, (const char*)Bs);
      __syncthreads();
    }
  }

  const float* biasz = (MODE == 0) ? ((z == 0) ? bias0 : bias1) : bias0;
  const int cc = lane & 15;
  const int cr = (lane >> 4) * 4;
#pragma unroll
  for (int i = 0; i < 4; ++i) {
    const int rowb = m0 + wm * 64 + i * 16 + cr;
#pragma unroll
    for (int j = 0; j < 4; ++j) {
      const int col = n0 + wn * 64 + j * 16 + cc;
#pragma unroll
      for (int r = 0; r < 4; ++r) {
        const int  row  = rowb + r;
        const long loff = (long)row * N + col;
        const long off  = (long)z * sC + loff;
        const float v   = acc[i][j][r];
        if (MODE == 0) {
          float o = v + biasz[col];
          if (z == 0) o *= 0.03125f;         // pre-scale q by 1/32 (exact)
          Cb[off] = __float2bfloat16(o);
        } else if (MODE == 1) {
          const unsigned mw = mask_bits[off >> 5];
          float sc = v + __bfloat162float(pbb[loff]);
          if (((mw >> (col & 31)) & 1u) == 0u) sc = -1e9f;
          Cb[off] = __float2bfloat16(__expf(fminf(sc, 60.0f)));
        } else if (MODE == 2) {
          Cb[off] = __float2bfloat16(v * inv_sum[z * S_ + row]);
        } else if (MODE == 3) {
          Cf[off] = v + biasz[col] + xres[off];
        } else {                             // MODE 4: bias by ROW (= h index)
          Cb[off] = __float2bfloat16(v + bias0[row]);
        }
      }
    }
  }
}

// ---- rownorm core (loop-safe: barrier after red reads)
__device__ __forceinline__ void rownorm_core(float* red, long row, const bf16* E,
                                             float* attn_f, float* inv_sum) {
  const int tid = threadIdx.x;
  const uint4 d = *(const uint4*)(E + row * (long)S_ + tid * 8);
  float ev[8];
  ev[0] = __uint_as_float(d.x << 16); ev[1] = __uint_as_float(d.x & 0xffff0000u);
  ev[2] = __uint_as_float(d.y << 16); ev[3] = __uint_as_float(d.y & 0xffff0000u);
  ev[4] = __uint_as_float(d.z << 16); ev[5] = __uint_as_float(d.z & 0xffff0000u);
  ev[6] = __uint_as_float(d.w << 16); ev[7] = __uint_as_float(d.w & 0xffff0000u);
  float s = 0.f;
#pragma unroll
  for (int i = 0; i < 8; ++i) s += ev[i];
  s = wave_reduce_sum(s);
  if ((tid & 63) == 0) red[tid >> 6] = s;
  __syncthreads();
  const float inv = 1.0f / fmaxf(red[0] + red[1] + red[2] + red[3], 1e-30f);
  __syncthreads();                           // red safe for next loop iteration
  if (tid == 0) inv_sum[row] = inv;
  float4 o0, o1;
  o0.x = bf16r(ev[0] * inv); o0.y = bf16r(ev[1] * inv);
  o0.z = bf16r(ev[2] * inv); o0.w = bf16r(ev[3] * inv);
  o1.x = bf16r(ev[4] * inv); o1.y = bf16r(ev[5] * inv);
  o1.z = bf16r(ev[6] * inv); o1.w = bf16r(ev[7] * inv);
  float4* dst = (float4*)(attn_f + row * (long)S_ + tid * 8);
  dst[0] = o0;
  dst[1] = o1;
}

// ---- layernorm core, float4 loads (loop-safe: collective barriers order red use)
__device__ __forceinline__ void ln_core(float* redA, float* redB, long row,
                                        float* h, const float* gamma,
                                        const float* beta) {
  float* hr = h + row * (long)H_;
  const int tid = threadIdx.x;
  const float4 v4 = ((const float4*)hr)[tid];
  float s = v4.x + v4.y + v4.z + v4.w;
  s = wave_reduce_sum(s);
  if ((tid & 63) == 0) redA[tid >> 6] = s;
  __syncthreads();
  const float mu = (redA[0] + redA[1] + redA[2] + redA[3]) * (1.0f / H_);
  const float dx = v4.x - mu, dy = v4.y - mu, dz = v4.z - mu, dw = v4.w - mu;
  float vs = dx * dx + dy * dy + dz * dz + dw * dw;
  vs = wave_reduce_sum(vs);
  if ((tid & 63) == 0) redB[tid >> 6] = vs;
  __syncthreads();
  const float var  = (redB[0] + redB[1] + redB[2] + redB[3]) * (1.0f / H_);
  const float rstd = rsqrtf(var + 1e-5f);
  const float4 g4 = ((const float4*)gamma)[tid];
  const float4 b4 = ((const float4*)beta)[tid];
  float4 o;
  o.x = bf16r(dx * rstd * g4.x + b4.x);
  o.y = bf16r(dy * rstd * g4.y + b4.y);
  o.z = bf16r(dz * rstd * g4.z + b4.z);
  o.w = bf16r(dw * rstd * g4.w + b4.w);
  ((float4*)hr)[tid] = o;
}

// ======================= cooperative mega kernel ================================
struct KArgs {
  const float* x; const int* mask;
  const float* Wq; const float* bq; const float* Wk; const float* bk;
  const float* Wv; const float* bv; const float* pos_bias;
  const float* Wo; const float* bo; const float* gamma; const float* beta;
  float* normed_f; float* attn_f;
  bf16* xpb; bf16* q_b; bf16* kbuf; bf16* vT; bf16* ctx; bf16* attn_b;
  bf16* wts; float* inv_sum; unsigned* mask_bits; bf16* pbb;
};

// 1024 blocks x 256 thr, 4 blocks/CU co-resident (32.03KB LDS, VGPR<=128).
// 7 phases separated by grid.sync(); each phase grid-strides its virtual blocks
// in the measured-best per-mode config (MODE 2 runs single-buffer: the 64KB dbuf
// would cap cooperative occupancy at 2 blocks/CU; dbuf measured ~neutral in r9).
__global__ void __launch_bounds__(256, 4) mega_kernel(KArgs a) {
  __shared__ bf16  As[128 * 64];   // 16 KB
  __shared__ bf16  Bs[128 * 64];   // 16 KB
  __shared__ float sred[8];
  cg::grid_group grid = cg::this_grid();
  const int nb = gridDim.x;        // 1024

  // P1: prep — 26624 vblocks
  for (int vb = blockIdx.x; vb < 26624; vb += nb)
    prep_core(vb, a.Wq, a.Wk, a.Wv, a.Wo, a.wts, a.x, a.xpb,
              a.mask, a.mask_bits, a.pos_bias, a.pbb);
  grid.sync();

  // P2: q,k proj (64x8x2 = 1024 vblocks) + vT (8x16x4 = 512 vblocks)
  for (int vb = blockIdx.x; vb < 1536; vb += nb) {
    if (vb < 1024) {
      const int bx = vb & 63, by = (vb >> 6) & 7, z = vb >> 9;
      gemm_core<0, false>(As, Bs, bx, by, z, a.xpb, 0, a.wts, HH,
                          a.q_b, nullptr, BSH, B_ * S_, H_, H_,
                          a.bq, a.bk, nullptr, nullptr, nullptr, nullptr);
    } else {
      const int w = vb - 1024, bx = w & 7, by = (w >> 3) & 15, z = w >> 7;
      gemm_core<4, false>(As, Bs, bx, by, z, a.wts + 2 * HH, 0, a.xpb, SH,
                          a.vT, nullptr, SH, H_, S_, H_,
                          a.bv, nullptr, nullptr, nullptr, nullptr, nullptr);
    }
  }
  grid.sync();

  // P3: E = exp((q/32)k^T + pbb, masked) — 16x16x4 = 1024 vblocks
  for (int vb = blockIdx.x; vb < 1024; vb += nb) {
    const int bx = vb & 15, by = (vb >> 4) & 15, z = vb >> 8;
    gemm_core<1, false>(As, Bs, bx, by, z, a.q_b, SH, a.kbuf, SH,
                        a.attn_b, nullptr, SS, S_, S_, H_,
                        nullptr, nullptr, a.pbb, a.mask_bits, nullptr, nullptr);
  }
  grid.sync();

  // P4: rownorm — 8192 rows
  for (int vb = blockIdx.x; vb < B_ * S_; vb += nb)
    rownorm_core(sred, vb, a.attn_b, a.attn_f, a.inv_sum);
  grid.sync();

  // P5: ctx = (E @ v) * inv_sum — 16x8x4 = 512 vblocks (K=2048)
  for (int vb = blockIdx.x; vb < 512; vb += nb) {
    const int bx = vb & 15, by = (vb >> 4) & 7, z = vb >> 7;
    gemm_core<2, false>(As, Bs, bx, by, z, a.attn_b, SS, a.vT, SH,
                        a.ctx, nullptr, SH, S_, H_, S_,
                        nullptr, nullptr, nullptr, nullptr, nullptr, a.inv_sum);
  }
  grid.sync();

  // P6: h = ctx Wo^T + bo + x — 64x8 = 512 vblocks
  for (int vb = blockIdx.x; vb < 512; vb += nb) {
    const int bx = vb & 63, by = vb >> 6;
    gemm_core<3, false>(As, Bs, bx, by, 0, a.ctx, 0, a.wts + 3 * HH, 0,
                        nullptr, a.normed_f, 0, B_ * S_, H_, H_,
                        a.bo, nullptr, nullptr, nullptr, a.x, nullptr);
  }
  grid.sync();

  // P7: layernorm — 8192 rows
  for (int vb = blockIdx.x; vb < B_ * S_; vb += nb)
    ln_core(sred, sred + 4, vb, a.normed_f, a.gamma, a.beta);
}

// ======================= fallback standalone kernels (r11 path) =================
__global__ void prep_kernel(const float* __restrict__ Wq, const float* __restrict__ Wk,
                            const float* __restrict__ Wv, const float* __restrict__ Wo,
                            bf16* __restrict__ wdst,
                            const float* __restrict__ x, bf16* __restrict__ xpb,
                            const int* __restrict__ mask, unsigned* __restrict__ mask_bits,
                            const float* __restrict__ pos_bias, bf16* __restrict__ pbb) {
  prep_core(blockIdx.x, Wq, Wk, Wv, Wo, wdst, x, xpb, mask, mask_bits, pos_bias, pbb);
}

template <int MODE, bool DBUF>
__global__ void gemm_nt(const bf16* __restrict__ A, long sA,
                        const bf16* __restrict__ Bm, long sB,
                        bf16* __restrict__ Cb, float* __restrict__ Cf, long sC,
                        int M, int N, int K,
                        const float* __restrict__ bias0,
                        const float* __restrict__ bias1,
                        const bf16* __restrict__ pbb,
                        const unsigned* __restrict__ mask_bits,
                        const float* __restrict__ xres,
                        const float* __restrict__ inv_sum) {
  constexpr int NBUF = DBUF ? 2 : 1;
  __shared__ bf16 As[NBUF * 128 * 64];
  __shared__ bf16 Bs[NBUF * 128 * 64];
  gemm_core<MODE, DBUF>(As, Bs, blockIdx.x, blockIdx.y, blockIdx.z,
                        A, sA, Bm, sB, Cb, Cf, sC, M, N, K,
                        bias0, bias1, pbb, mask_bits, xres, inv_sum);
}

__global__ void rownorm_kernel(const bf16* __restrict__ E, float* __restrict__ attn_f,
                               float* __restrict__ inv_sum) {
  __shared__ float red[4];
  rownorm_core(red, blockIdx.x, E, attn_f, inv_sum);
}

__global__ void ln_kernel(float* __restrict__ h, const float* __restrict__ gamma,
                          const float* __restrict__ beta) {
  __shared__ float redA[4], redB[4];
  ln_core(redA, redB, blockIdx.x, h, gamma, beta);
}

extern "C" void kernel_launch(void* const* d_in, const int* in_sizes, int n_in,
                              void* d_out, int out_size, void* d_ws, size_t ws_size,
                              hipStream_t stream) {
  const float* x        = (const float*)d_in[0];
  const int*   mask     = (const int*)d_in[1];
  const float* Wq       = (const float*)d_in[2];
  const float* bq       = (const float*)d_in[3];
  const float* Wk       = (const float*)d_in[4];
  const float* bk       = (const float*)d_in[5];
  const float* Wv       = (const float*)d_in[6];
  const float* bv       = (const float*)d_in[7];
  const float* pos_bias = (const float*)d_in[8];
  const float* Wo       = (const float*)d_in[9];
  const float* bo       = (const float*)d_in[10];
  const float* gamma    = (const float*)d_in[11];
  const float* beta     = (const float*)d_in[12];

  float* normed_f = (float*)d_out;
  float* attn_f   = (float*)((char*)d_out + ((size_t)32 << 20));

  const size_t MiB = (size_t)1 << 20;
  bf16*     xpb       = (bf16*)d_ws;                          // [  0, 16)
  bf16*     q_b       = (bf16*)((char*)d_ws +  16 * MiB);     // [ 16, 32)
  bf16*     kbuf      = (bf16*)((char*)d_ws +  32 * MiB);     // [ 32, 48)
  bf16*     vT        = (bf16*)((char*)d_ws +  64 * MiB);     // [ 64, 80)
  bf16*     ctx       = (bf16*)((char*)d_ws +  80 * MiB);     // [ 80, 96)
  bf16*     attn_b    = (bf16*)((char*)d_ws +  96 * MiB);     // [ 96,128)
  bf16*     wts       = (bf16*)((char*)d_ws + 128 * MiB);     // [128,136)
  float*    inv_sum   = (float*)((char*)d_ws + 136 * MiB);    // 32 KB
  unsigned* mask_bits = (unsigned*)((char*)d_ws + 137 * MiB); // 2 MiB
  bf16*     pbb       = (bf16*)((char*)d_ws + 139 * MiB);     // 8 MiB
  bf16* Wvb = wts + 2 * HH, *Wob = wts + 3 * HH;

  const int MQKV = B_ * S_;   // 8192

  // ---- preferred: single cooperative launch (kills ~6 x ~11us dispatch gaps)
  KArgs ha;
  ha.x = x; ha.mask = mask; ha.Wq = Wq; ha.bq = bq; ha.Wk = Wk; ha.bk = bk;
  ha.Wv = Wv; ha.bv = bv; ha.pos_bias = pos_bias; ha.Wo = Wo; ha.bo = bo;
  ha.gamma = gamma; ha.beta = beta; ha.normed_f = normed_f; ha.attn_f = attn_f;
  ha.xpb = xpb; ha.q_b = q_b; ha.kbuf = kbuf; ha.vT = vT; ha.ctx = ctx;
  ha.attn_b = attn_b; ha.wts = wts; ha.inv_sum = inv_sum;
  ha.mask_bits = mask_bits; ha.pbb = pbb;
  void* kp[] = { &ha };
  hipError_t err = hipLaunchCooperativeKernel((void*)mega_kernel, dim3(1024),
                                              dim3(256), kp, 0, stream);
  if (err == hipSuccess) return;

  // ---- fallback: r11 multi-launch path (identical math)
  prep_kernel<<<dim3(26624), 256, 0, stream>>>(Wq, Wk, Wv, Wo, wts, x, xpb,
                                               mask, mask_bits, pos_bias, pbb);
  gemm_nt<0, false><<<dim3(64, 8, 2), 256, 0, stream>>>(xpb, 0, wts, HH, q_b, nullptr, BSH,
                                                        MQKV, H_, H_, bq, bk,
                                                        nullptr, nullptr, nullptr, nullptr);
  gemm_nt<4, false><<<dim3(8, 16, 4), 256, 0, stream>>>(Wvb, 0, xpb, SH, vT, nullptr, SH,
                                                        H_, S_, H_, bv, nullptr,
                                                        nullptr, nullptr, nullptr, nullptr);
  gemm_nt<1, false><<<dim3(16, 16, B_), 256, 0, stream>>>(q_b, SH, kbuf, SH,
                                                          attn_b, nullptr, SS,
                                                          S_, S_, H_, nullptr, nullptr,
                                                          pbb, mask_bits, nullptr, nullptr);
  rownorm_kernel<<<B_ * S_, 256, 0, stream>>>(attn_b, attn_f, inv_sum);
  gemm_nt<2, true><<<dim3(16, 8, B_), 256, 0, stream>>>(attn_b, SS, vT, SH,
                                                        ctx, nullptr, SH,
                                                        S_, H_, S_, nullptr, nullptr,
                                                        nullptr, nullptr, nullptr, inv_sum);
  gemm_nt<3, false><<<dim3(64, 8, 1), 256, 0, stream>>>(ctx, 0, Wob, 0, nullptr, normed_f, 0,
                                                        MQKV, H_, H_, bo, nullptr,
                                                        nullptr, nullptr, x, nullptr);
  ln_kernel<<<B_ * S_, 256, 0, stream>>>(normed_f, gamma, beta);
}

// Round 13
// 415.585 us; speedup vs baseline: 2.9063x; 2.9063x over previous
//
#include <hip/hip_runtime.h>
#include <hip/hip_bf16.h>
#include <math.h>

typedef __hip_bfloat16 bf16;
typedef __bf16 bf16x8 __attribute__((ext_vector_type(8)));
typedef float f32x4 __attribute__((ext_vector_type(4)));

static constexpr int  B_  = 4, S_ = 2048, H_ = 1024;
static constexpr long BSH = (long)B_ * S_ * H_;   // 8,388,608
static constexpr long SH  = (long)S_ * H_;        // 2,097,152
static constexpr long SS  = (long)S_ * S_;        // 4,194,304
static constexpr long HH  = (long)H_ * H_;        // 1,048,576

// async global->LDS, 16B per lane; LDS dest is wave-uniform base + lane*16
#define GLOAD_LDS16(gp, lp)                                                          \
  __builtin_amdgcn_global_load_lds((__attribute__((address_space(1))) void*)(gp),    \
                                   (__attribute__((address_space(3))) void*)(lp),    \
                                   16, 0, 0)

// raw barrier (does NOT drain vmcnt) + compiler memory fence
#define BARRIER() do { __builtin_amdgcn_s_barrier(); asm volatile("" ::: "memory"); } while (0)

template <int N> __device__ __forceinline__ void waitcnt_vm() {
  if constexpr (N == 0)      asm volatile("s_waitcnt vmcnt(0)" ::: "memory");
  else if constexpr (N == 8) asm volatile("s_waitcnt vmcnt(8)" ::: "memory");
}

__device__ __forceinline__ float wave_reduce_sum(float v) {
#pragma unroll
  for (int o = 32; o; o >>= 1) v += __shfl_xor(v, o, 64);
  return v;
}
__device__ __forceinline__ float bf16r(float v) {
  return __bfloat162float(__float2bfloat16(v));
}

// ================= device cores =================================================

// ---- prep virtual-block: weights (0..4095) + PE-add (4096..20479)
//      + mask bit-pack (20480..22527) + pos_bias->bf16 (22528..26623)
__device__ __forceinline__ void prep_core(
    int bx, const float* Wq, const float* Wk, const float* Wv, const float* Wo,
    bf16* wdst, const float* x, bf16* xpb,
    const int* mask, unsigned* mask_bits, const float* pos_bias, bf16* pbb) {
  const int tid = threadIdx.x;
  if (bx < 4096) {
    const int w = bx >> 10;
    const float* src = (w == 0) ? Wq : (w == 1) ? Wk : (w == 2) ? Wv : Wo;
    bf16* d = wdst + (long)w * HH;
    const int idx = ((bx & 1023) << 8) + tid;
    const float4 f = ((const float4*)src)[idx];
    d[idx * 4 + 0] = __float2bfloat16(f.x);
    d[idx * 4 + 1] = __float2bfloat16(f.y);
    d[idx * 4 + 2] = __float2bfloat16(f.z);
    d[idx * 4 + 3] = __float2bfloat16(f.w);
  } else if (bx < 20480) {
    const long idx = (((long)(bx - 4096)) << 8) + tid;     // over B*S*(H/2)
    const int  i   = (int)(idx & (H_ / 2 - 1));
    const long bs  = idx >> 9;
    const int  s   = (int)(bs & (S_ - 1));
    const float div = __expf((float)(2 * i) * (-9.210340371976184f / (float)H_));
    const float ang = (float)s * div;
    const float2 xv = ((const float2*)x)[idx];
    xpb[idx * 2 + 0] = __float2bfloat16(xv.x + __sinf(ang));
    xpb[idx * 2 + 1] = __float2bfloat16(xv.y + __cosf(ang));
  } else if (bx < 22528) {
    const long uidx = (((long)(bx - 20480)) << 8) + tid;
    const int4* mp  = (const int4*)mask + uidx * 8;
    unsigned bits = 0;
#pragma unroll
    for (int q = 0; q < 8; ++q) {
      const int4 v = mp[q];
      bits |= (v.x ? 1u : 0u) << (q * 4 + 0);
      bits |= (v.y ? 1u : 0u) << (q * 4 + 1);
      bits |= (v.z ? 1u : 0u) << (q * 4 + 2);
      bits |= (v.w ? 1u : 0u) << (q * 4 + 3);
    }
    mask_bits[uidx] = bits;
  } else {
    const long idx = (((long)(bx - 22528)) << 8) + tid;
    const float4 f = ((const float4*)pos_bias)[idx];
    bf16* d = pbb + idx * 4;
    d[0] = __float2bfloat16(f.x);
    d[1] = __float2bfloat16(f.y);
    d[2] = __float2bfloat16(f.z);
    d[3] = __float2bfloat16(f.w);
  }
}

// ---- NT GEMM core, 128x128 tile, BK=64, 256 thr. As/Bs point to NBUF x 16KB.
// DBUF=false: stage -> syncthreads(drain) -> compute -> syncthreads (r6 winner,
//             best for K=1024 modes at ~4 blocks/CU).
// DBUF=true : counted-vmcnt double-buffer (r7) — MODE 2 only (K=2048).
// Read-side k-slot XOR (row&7) swizzle; inverse perm on GLOBAL source (rule 21;
// conflicts measured 0).
// MODE 0: Cb = bf16(acc + biasz[col]); z==0 scaled 1/32 (exact exponent shift)
// MODE 1: Cb = bf16(exp(clamp(acc + pbb, maskbit)))   (acc pre-scaled)
// MODE 2: Cb = bf16(acc * inv_sum[z*S+row])
// MODE 3: Cf = acc + bias0[col] + xres[m,n]  (fp32)
// MODE 4: Cb = bf16(acc + bias0[ROW])        (vT = Wv @ xpb^T + bv, H x S out)
template <int MODE, bool DBUF>
__device__ __forceinline__ void gemm_core(
    bf16* As, bf16* Bs, int bxx, int byy, int z,
    const bf16* A, long sA, const bf16* Bm, long sB,
    bf16* Cb, float* Cf, long sC, int M, int N, int K,
    const float* bias0, const float* bias1,
    const bf16* pbb, const unsigned* mask_bits,
    const float* xres, const float* inv_sum) {
  constexpr int BM = 128, BN = 128, BK = 64;
  constexpr int TILE = BM * BK;              // 8192 bf16 = 16KB

  const int tid  = threadIdx.x;
  const int lane = tid & 63;
  const int wave = tid >> 6;
  const int wm   = wave & 1;
  const int wn   = wave >> 1;
  const int m0   = bxx * BM;
  const int n0   = byy * BN;

  const bf16* Ab = A  + (long)z * sA;
  const bf16* Bb = Bm + (long)z * sB;

  const int rw = tid >> 3;                   // base row (rows rw+32q)
  const int cp = (tid & 7) ^ (rw & 7);       // permuted global 16B-colslot
  const bf16* ga = Ab + (long)(m0 + rw) * K + cp * 8;
  const bf16* gb = Bb + (long)(n0 + rw) * K + cp * 8;

  auto stage = [&](int tile, int buf) {
    const long k0 = (long)tile * BK;
#pragma unroll
    for (int q = 0; q < 4; ++q) {
      GLOAD_LDS16(ga + (long)(32 * q) * K + k0, As + buf * TILE + tid * 8 + q * 2048);
      GLOAD_LDS16(gb + (long)(32 * q) * K + k0, Bs + buf * TILE + tid * 8 + q * 2048);
    }
  };

  f32x4 acc[4][4] = {};

  const int fr     = lane & 15;
  const int k0slot = lane >> 4;
  const int sw     = fr & 7;

  auto tile_compute = [&](const char* bAc, const char* bBc) {
#pragma unroll
    for (int ks = 0; ks < 2; ++ks) {
      const int co = ((k0slot + 4 * ks) ^ sw) << 4;
      bf16x8 af[4], bfv[4];
#pragma unroll
      for (int i = 0; i < 4; ++i) {
        af[i]  = *(const bf16x8*)(bAc + (wm * 64 + i * 16 + fr) * 128 + co);
        bfv[i] = *(const bf16x8*)(bBc + (wn * 64 + i * 16 + fr) * 128 + co);
      }
#pragma unroll
      for (int i = 0; i < 4; ++i)
#pragma unroll
        for (int j = 0; j < 4; ++j)
          acc[i][j] = __builtin_amdgcn_mfma_f32_16x16x32_bf16(af[i], bfv[j], acc[i][j], 0, 0, 0);
    }
  };

  const int nkt = K / BK;
  if constexpr (DBUF) {
    stage(0, 0);
    for (int kt = 0; kt < nkt; ++kt) {
      const int cur = kt & 1;
      if (kt + 1 < nkt) {
        stage(kt + 1, cur ^ 1);
        waitcnt_vm<8>();
      } else {
        waitcnt_vm<0>();
      }
      BARRIER();
      tile_compute((const char*)(As + cur * TILE), (const char*)(Bs + cur * TILE));
      BARRIER();
    }
  } else {
    for (int kt = 0; kt < nkt; ++kt) {
      stage(kt, 0);
      __syncthreads();
      tile_compute((const char*)As, (const char*)Bs);
      __syncthreads();
    }
  }

  const float* biasz = (MODE == 0) ? ((z == 0) ? bias0 : bias1) : bias0;
  const int cc = lane & 15;
  const int cr = (lane >> 4) * 4;
#pragma unroll
  for (int i = 0; i < 4; ++i) {
    const int rowb = m0 + wm * 64 + i * 16 + cr;
#pragma unroll
    for (int j = 0; j < 4; ++j) {
      const int col = n0 + wn * 64 + j * 16 + cc;
#pragma unroll
      for (int r = 0; r < 4; ++r) {
        const int  row  = rowb + r;
        const long loff = (long)row * N + col;
        const long off  = (long)z * sC + loff;
        const float v   = acc[i][j][r];
        if (MODE == 0) {
          float o = v + biasz[col];
          if (z == 0) o *= 0.03125f;         // pre-scale q by 1/32 (exact)
          Cb[off] = __float2bfloat16(o);
        } else if (MODE == 1) {
          const unsigned mw = mask_bits[off >> 5];
          float sc = v + __bfloat162float(pbb[loff]);
          if (((mw >> (col & 31)) & 1u) == 0u) sc = -1e9f;
          Cb[off] = __float2bfloat16(__expf(fminf(sc, 60.0f)));
        } else if (MODE == 2) {
          Cb[off] = __float2bfloat16(v * inv_sum[z * S_ + row]);
        } else if (MODE == 3) {
          Cf[off] = v + biasz[col] + xres[off];
        } else {                             // MODE 4: bias by ROW (= h index)
          Cb[off] = __float2bfloat16(v + bias0[row]);
        }
      }
    }
  }
}

// ================= kernels ======================================================

__global__ void prep_kernel(const float* __restrict__ Wq, const float* __restrict__ Wk,
                            const float* __restrict__ Wv, const float* __restrict__ Wo,
                            bf16* __restrict__ wdst,
                            const float* __restrict__ x, bf16* __restrict__ xpb,
                            const int* __restrict__ mask, unsigned* __restrict__ mask_bits,
                            const float* __restrict__ pos_bias, bf16* __restrict__ pbb) {
  prep_core(blockIdx.x, Wq, Wk, Wv, Wo, wdst, x, xpb, mask, mask_bits, pos_bias, pbb);
}

// Merged q,k projection (vblocks 0..1023 = 64x8x2) + vT (1024..1535 = 8x16x4).
// Both depend only on prep; merging kills one dispatch gap (~13us). Each vblock
// is a self-contained r6-style single-buffer GEMM.
__global__ void qkvt_kernel(const bf16* __restrict__ xpb, const bf16* __restrict__ wts,
                            bf16* __restrict__ q_b, bf16* __restrict__ vT,
                            const float* __restrict__ bq, const float* __restrict__ bk,
                            const float* __restrict__ bv) {
  __shared__ bf16 As[128 * 64];
  __shared__ bf16 Bs[128 * 64];
  const int vb = blockIdx.x;
  if (vb < 1024) {
    const int bx = vb & 63, by = (vb >> 6) & 7, z = vb >> 9;
    gemm_core<0, false>(As, Bs, bx, by, z, xpb, 0, wts, HH,
                        q_b, nullptr, BSH, B_ * S_, H_, H_,
                        bq, bk, nullptr, nullptr, nullptr, nullptr);
  } else {
    const int w = vb - 1024, bx = w & 7, by = (w >> 3) & 15, z = w >> 7;
    gemm_core<4, false>(As, Bs, bx, by, z, wts + 2 * HH, 0, xpb, SH,
                        vT, nullptr, SH, H_, S_, H_,
                        bv, nullptr, nullptr, nullptr, nullptr, nullptr);
  }
}

template <int MODE, bool DBUF>
__global__ void gemm_nt(const bf16* __restrict__ A, long sA,
                        const bf16* __restrict__ Bm, long sB,
                        bf16* __restrict__ Cb, float* __restrict__ Cf, long sC,
                        int M, int N, int K,
                        const float* __restrict__ bias0,
                        const float* __restrict__ bias1,
                        const bf16* __restrict__ pbb,
                        const unsigned* __restrict__ mask_bits,
                        const float* __restrict__ xres,
                        const float* __restrict__ inv_sum) {
  constexpr int NBUF = DBUF ? 2 : 1;
  __shared__ bf16 As[NBUF * 128 * 64];
  __shared__ bf16 Bs[NBUF * 128 * 64];
  gemm_core<MODE, DBUF>(As, Bs, blockIdx.x, blockIdx.y, blockIdx.z,
                        A, sA, Bm, sB, Cb, Cf, sC, M, N, K,
                        bias0, bias1, pbb, mask_bits, xres, inv_sum);
}

__global__ void rownorm_kernel(const bf16* __restrict__ E, float* __restrict__ attn_f,
                               float* __restrict__ inv_sum) {
  const long row = blockIdx.x;
  const int  tid = threadIdx.x;
  const uint4 d = *(const uint4*)(E + row * (long)S_ + tid * 8);
  float ev[8];
  ev[0] = __uint_as_float(d.x << 16); ev[1] = __uint_as_float(d.x & 0xffff0000u);
  ev[2] = __uint_as_float(d.y << 16); ev[3] = __uint_as_float(d.y & 0xffff0000u);
  ev[4] = __uint_as_float(d.z << 16); ev[5] = __uint_as_float(d.z & 0xffff0000u);
  ev[6] = __uint_as_float(d.w << 16); ev[7] = __uint_as_float(d.w & 0xffff0000u);
  float s = 0.f;
#pragma unroll
  for (int i = 0; i < 8; ++i) s += ev[i];
  s = wave_reduce_sum(s);
  __shared__ float red[4];
  if ((tid & 63) == 0) red[tid >> 6] = s;
  __syncthreads();
  const float inv = 1.0f / fmaxf(red[0] + red[1] + red[2] + red[3], 1e-30f);
  if (tid == 0) inv_sum[row] = inv;
  float4 o0, o1;
  o0.x = bf16r(ev[0] * inv); o0.y = bf16r(ev[1] * inv);
  o0.z = bf16r(ev[2] * inv); o0.w = bf16r(ev[3] * inv);
  o1.x = bf16r(ev[4] * inv); o1.y = bf16r(ev[5] * inv);
  o1.z = bf16r(ev[6] * inv); o1.w = bf16r(ev[7] * inv);
  float4* dst = (float4*)(attn_f + row * (long)S_ + tid * 8);
  dst[0] = o0;
  dst[1] = o1;
}

__global__ void ln_kernel(float* __restrict__ h, const float* __restrict__ gamma,
                          const float* __restrict__ beta) {
  const long row = blockIdx.x;
  float* hr = h + row * (long)H_;
  const int tid = threadIdx.x;
  const float4 v4 = ((const float4*)hr)[tid];
  float s = v4.x + v4.y + v4.z + v4.w;
  s = wave_reduce_sum(s);
  __shared__ float redA[4], redB[4];
  if ((tid & 63) == 0) redA[tid >> 6] = s;
  __syncthreads();
  const float mu = (redA[0] + redA[1] + redA[2] + redA[3]) * (1.0f / H_);
  const float dx = v4.x - mu, dy = v4.y - mu, dz = v4.z - mu, dw = v4.w - mu;
  float vs = dx * dx + dy * dy + dz * dz + dw * dw;
  vs = wave_reduce_sum(vs);
  if ((tid & 63) == 0) redB[tid >> 6] = vs;
  __syncthreads();
  const float var  = (redB[0] + redB[1] + redB[2] + redB[3]) * (1.0f / H_);
  const float rstd = rsqrtf(var + 1e-5f);
  const float4 g4 = ((const float4*)gamma)[tid];
  const float4 b4 = ((const float4*)beta)[tid];
  float4 o;
  o.x = bf16r(dx * rstd * g4.x + b4.x);
  o.y = bf16r(dy * rstd * g4.y + b4.y);
  o.z = bf16r(dz * rstd * g4.z + b4.z);
  o.w = bf16r(dw * rstd * g4.w + b4.w);
  ((float4*)hr)[tid] = o;
}

extern "C" void kernel_launch(void* const* d_in, const int* in_sizes, int n_in,
                              void* d_out, int out_size, void* d_ws, size_t ws_size,
                              hipStream_t stream) {
  const float* x        = (const float*)d_in[0];
  const int*   mask     = (const int*)d_in[1];
  const float* Wq       = (const float*)d_in[2];
  const float* bq       = (const float*)d_in[3];
  const float* Wk       = (const float*)d_in[4];
  const float* bk       = (const float*)d_in[5];
  const float* Wv       = (const float*)d_in[6];
  const float* bv       = (const float*)d_in[7];
  const float* pos_bias = (const float*)d_in[8];
  const float* Wo       = (const float*)d_in[9];
  const float* bo       = (const float*)d_in[10];
  const float* gamma    = (const float*)d_in[11];
  const float* beta     = (const float*)d_in[12];

  // fp32 outputs: normed [0,32MiB), attn [32,96MiB)
  float* normed_f = (float*)d_out;
  float* attn_f   = (float*)((char*)d_out + ((size_t)32 << 20));

  const size_t MiB = (size_t)1 << 20;
  bf16*     xpb       = (bf16*)d_ws;                          // [  0, 16)
  bf16*     q_b       = (bf16*)((char*)d_ws +  16 * MiB);     // [ 16, 32)
  bf16*     kbuf      = (bf16*)((char*)d_ws +  32 * MiB);     // [ 32, 48)
  bf16*     vT        = (bf16*)((char*)d_ws +  64 * MiB);     // [ 64, 80)
  bf16*     ctx       = (bf16*)((char*)d_ws +  80 * MiB);     // [ 80, 96)
  bf16*     attn_b    = (bf16*)((char*)d_ws +  96 * MiB);     // [ 96,128)
  bf16*     wts       = (bf16*)((char*)d_ws + 128 * MiB);     // [128,136)
  float*    inv_sum   = (float*)((char*)d_ws + 136 * MiB);    // 32 KB
  unsigned* mask_bits = (unsigned*)((char*)d_ws + 137 * MiB); // 2 MiB
  bf16*     pbb       = (bf16*)((char*)d_ws + 139 * MiB);     // 8 MiB
  bf16* Wob = wts + 3 * HH;

  const int MQKV = B_ * S_;   // 8192

  // 1) prep: weights (4096) + xpb (16384) + mask bits (2048) + pos_bias bf16 (4096)
  prep_kernel<<<dim3(26624), 256, 0, stream>>>(Wq, Wk, Wv, Wo, wts, x, xpb,
                                               mask, mask_bits, pos_bias, pbb);

  // 2) q,k proj + vT in ONE dispatch (independent work; kills one launch gap)
  qkvt_kernel<<<dim3(1536), 256, 0, stream>>>(xpb, wts, q_b, vT, bq, bk, bv);

  // 3) E = exp((q/32)*k^T + pbb, masked) -> bf16 (single-buffer — measured best)
  gemm_nt<1, false><<<dim3(16, 16, B_), 256, 0, stream>>>(q_b, SH, kbuf, SH,
                                                          attn_b, nullptr, SS,
                                                          S_, S_, H_, nullptr, nullptr,
                                                          pbb, mask_bits, nullptr, nullptr);

  // 4) rownorm: inv_sum + normalized fp32 attn output
  rownorm_kernel<<<B_ * S_, 256, 0, stream>>>(attn_b, attn_f, inv_sum);

  // 5) ctx = (E @ v) * inv_sum  (K=2048 — dbuf counted-vmcnt)
  gemm_nt<2, true><<<dim3(16, 8, B_), 256, 0, stream>>>(attn_b, SS, vT, SH,
                                                        ctx, nullptr, SH,
                                                        S_, H_, S_, nullptr, nullptr,
                                                        nullptr, nullptr, nullptr, inv_sum);

  // 6) h = ctx * Wo^T + bo + x (single-buffer)
  gemm_nt<3, false><<<dim3(64, 8, 1), 256, 0, stream>>>(ctx, 0, Wob, 0, nullptr, normed_f, 0,
                                                        MQKV, H_, H_, bo, nullptr,
                                                        nullptr, nullptr, x, nullptr);

  // 7) layernorm in-place (row-local)
  ln_kernel<<<B_ * S_, 256, 0, stream>>>(normed_f, gamma, beta);
}

// Round 14
// 393.863 us; speedup vs baseline: 3.0665x; 1.0551x over previous
//
#include <hip/hip_runtime.h>
#include <hip/hip_bf16.h>
#include <math.h>

typedef __hip_bfloat16 bf16;
typedef __bf16 bf16x8 __attribute__((ext_vector_type(8)));
typedef float f32x4 __attribute__((ext_vector_type(4)));

static constexpr int  B_  = 4, S_ = 2048, H_ = 1024;
static constexpr long BSH = (long)B_ * S_ * H_;   // 8,388,608
static constexpr long SH  = (long)S_ * H_;        // 2,097,152
static constexpr long SS  = (long)S_ * S_;        // 4,194,304
static constexpr long HH  = (long)H_ * H_;        // 1,048,576

// async global->LDS, 16B per lane; LDS dest is wave-uniform base + lane*16
#define GLOAD_LDS16(gp, lp)                                                          \
  __builtin_amdgcn_global_load_lds((__attribute__((address_space(1))) void*)(gp),    \
                                   (__attribute__((address_space(3))) void*)(lp),    \
                                   16, 0, 0)

// raw barrier (does NOT drain vmcnt) + compiler memory fence
#define BARRIER() do { __builtin_amdgcn_s_barrier(); asm volatile("" ::: "memory"); } while (0)

template <int N> __device__ __forceinline__ void waitcnt_vm() {
  if constexpr (N == 0)      asm volatile("s_waitcnt vmcnt(0)" ::: "memory");
  else if constexpr (N == 8) asm volatile("s_waitcnt vmcnt(8)" ::: "memory");
}

__device__ __forceinline__ float wave_reduce_sum(float v) {
#pragma unroll
  for (int o = 32; o; o >>= 1) v += __shfl_xor(v, o, 64);
  return v;
}
__device__ __forceinline__ float bf16r(float v) {
  return __bfloat162float(__float2bfloat16(v));
}

// ================= device cores =================================================

// ---- prep virtual-block: weights (0..4095) + PE-add (4096..20479)
//      + mask bit-pack (20480..22527) + pos_bias->bf16 (22528..26623)
__device__ __forceinline__ void prep_core(
    int bx, const float* Wq, const float* Wk, const float* Wv, const float* Wo,
    bf16* wdst, const float* x, bf16* xpb,
    const int* mask, unsigned* mask_bits, const float* pos_bias, bf16* pbb) {
  const int tid = threadIdx.x;
  if (bx < 4096) {
    const int w = bx >> 10;
    const float* src = (w == 0) ? Wq : (w == 1) ? Wk : (w == 2) ? Wv : Wo;
    bf16* d = wdst + (long)w * HH;
    const int idx = ((bx & 1023) << 8) + tid;
    const float4 f = ((const float4*)src)[idx];
    d[idx * 4 + 0] = __float2bfloat16(f.x);
    d[idx * 4 + 1] = __float2bfloat16(f.y);
    d[idx * 4 + 2] = __float2bfloat16(f.z);
    d[idx * 4 + 3] = __float2bfloat16(f.w);
  } else if (bx < 20480) {
    const long idx = (((long)(bx - 4096)) << 8) + tid;     // over B*S*(H/2)
    const int  i   = (int)(idx & (H_ / 2 - 1));
    const long bs  = idx >> 9;
    const int  s   = (int)(bs & (S_ - 1));
    const float div = __expf((float)(2 * i) * (-9.210340371976184f / (float)H_));
    const float ang = (float)s * div;
    const float2 xv = ((const float2*)x)[idx];
    xpb[idx * 2 + 0] = __float2bfloat16(xv.x + __sinf(ang));
    xpb[idx * 2 + 1] = __float2bfloat16(xv.y + __cosf(ang));
  } else if (bx < 22528) {
    const long uidx = (((long)(bx - 20480)) << 8) + tid;
    const int4* mp  = (const int4*)mask + uidx * 8;
    unsigned bits = 0;
#pragma unroll
    for (int q = 0; q < 8; ++q) {
      const int4 v = mp[q];
      bits |= (v.x ? 1u : 0u) << (q * 4 + 0);
      bits |= (v.y ? 1u : 0u) << (q * 4 + 1);
      bits |= (v.z ? 1u : 0u) << (q * 4 + 2);
      bits |= (v.w ? 1u : 0u) << (q * 4 + 3);
    }
    mask_bits[uidx] = bits;
  } else {
    const long idx = (((long)(bx - 22528)) << 8) + tid;
    const float4 f = ((const float4*)pos_bias)[idx];
    bf16* d = pbb + idx * 4;
    d[0] = __float2bfloat16(f.x);
    d[1] = __float2bfloat16(f.y);
    d[2] = __float2bfloat16(f.z);
    d[3] = __float2bfloat16(f.w);
  }
}

// ---- NT GEMM core, 128x128 tile, BK=64, 256 thr. As/Bs point to NBUF x 16KB.
// DBUF=false: stage -> syncthreads(drain) -> compute -> syncthreads (r6 winner).
// Read-side k-slot XOR (row&7) swizzle; inverse perm on GLOBAL source (rule 21;
// conflicts measured 0).
// MODE 0: Cb = bf16(acc + biasz[col]); z==0 scaled 1/32 (exact exponent shift)
// MODE 1: Cb = bf16(exp(clamp(acc + pbb, maskbit)))   (acc pre-scaled)
// MODE 2: Cb = bf16(acc)  — UNNORMALIZED ctx' = E@v (inv_sum deferred to MODE 3)
// MODE 3: Cf = inv_sum[row]*acc + bias0[col] + xres[m,n]  (fp32; normalization
//         commutes: scaling A-rows == scaling output rows)
// MODE 4: Cb = bf16(acc + bias0[ROW])        (vT = Wv @ xpb^T + bv, H x S out)
template <int MODE, bool DBUF>
__device__ __forceinline__ void gemm_core(
    bf16* As, bf16* Bs, int bxx, int byy, int z,
    const bf16* A, long sA, const bf16* Bm, long sB,
    bf16* Cb, float* Cf, long sC, int M, int N, int K,
    const float* bias0, const float* bias1,
    const bf16* pbb, const unsigned* mask_bits,
    const float* xres, const float* inv_sum) {
  constexpr int BM = 128, BN = 128, BK = 64;
  constexpr int TILE = BM * BK;              // 8192 bf16 = 16KB

  const int tid  = threadIdx.x;
  const int lane = tid & 63;
  const int wave = tid >> 6;
  const int wm   = wave & 1;
  const int wn   = wave >> 1;
  const int m0   = bxx * BM;
  const int n0   = byy * BN;

  const bf16* Ab = A  + (long)z * sA;
  const bf16* Bb = Bm + (long)z * sB;

  const int rw = tid >> 3;                   // base row (rows rw+32q)
  const int cp = (tid & 7) ^ (rw & 7);       // permuted global 16B-colslot
  const bf16* ga = Ab + (long)(m0 + rw) * K + cp * 8;
  const bf16* gb = Bb + (long)(n0 + rw) * K + cp * 8;

  auto stage = [&](int tile, int buf) {
    const long k0 = (long)tile * BK;
#pragma unroll
    for (int q = 0; q < 4; ++q) {
      GLOAD_LDS16(ga + (long)(32 * q) * K + k0, As + buf * TILE + tid * 8 + q * 2048);
      GLOAD_LDS16(gb + (long)(32 * q) * K + k0, Bs + buf * TILE + tid * 8 + q * 2048);
    }
  };

  f32x4 acc[4][4] = {};

  const int fr     = lane & 15;
  const int k0slot = lane >> 4;
  const int sw     = fr & 7;

  auto tile_compute = [&](const char* bAc, const char* bBc) {
#pragma unroll
    for (int ks = 0; ks < 2; ++ks) {
      const int co = ((k0slot + 4 * ks) ^ sw) << 4;
      bf16x8 af[4], bfv[4];
#pragma unroll
      for (int i = 0; i < 4; ++i) {
        af[i]  = *(const bf16x8*)(bAc + (wm * 64 + i * 16 + fr) * 128 + co);
        bfv[i] = *(const bf16x8*)(bBc + (wn * 64 + i * 16 + fr) * 128 + co);
      }
#pragma unroll
      for (int i = 0; i < 4; ++i)
#pragma unroll
        for (int j = 0; j < 4; ++j)
          acc[i][j] = __builtin_amdgcn_mfma_f32_16x16x32_bf16(af[i], bfv[j], acc[i][j], 0, 0, 0);
    }
  };

  const int nkt = K / BK;
  if constexpr (DBUF) {
    stage(0, 0);
    for (int kt = 0; kt < nkt; ++kt) {
      const int cur = kt & 1;
      if (kt + 1 < nkt) {
        stage(kt + 1, cur ^ 1);
        waitcnt_vm<8>();
      } else {
        waitcnt_vm<0>();
      }
      BARRIER();
      tile_compute((const char*)(As + cur * TILE), (const char*)(Bs + cur * TILE));
      BARRIER();
    }
  } else {
    for (int kt = 0; kt < nkt; ++kt) {
      stage(kt, 0);
      __syncthreads();
      tile_compute((const char*)As, (const char*)Bs);
      __syncthreads();
    }
  }

  const float* biasz = (MODE == 0) ? ((z == 0) ? bias0 : bias1) : bias0;
  const int cc = lane & 15;
  const int cr = (lane >> 4) * 4;
#pragma unroll
  for (int i = 0; i < 4; ++i) {
    const int rowb = m0 + wm * 64 + i * 16 + cr;
#pragma unroll
    for (int j = 0; j < 4; ++j) {
      const int col = n0 + wn * 64 + j * 16 + cc;
#pragma unroll
      for (int r = 0; r < 4; ++r) {
        const int  row  = rowb + r;
        const long loff = (long)row * N + col;
        const long off  = (long)z * sC + loff;
        const float v   = acc[i][j][r];
        if (MODE == 0) {
          float o = v + biasz[col];
          if (z == 0) o *= 0.03125f;         // pre-scale q by 1/32 (exact)
          Cb[off] = __float2bfloat16(o);
        } else if (MODE == 1) {
          const unsigned mw = mask_bits[off >> 5];
          float sc = v + __bfloat162float(pbb[loff]);
          if (((mw >> (col & 31)) & 1u) == 0u) sc = -1e9f;
          Cb[off] = __float2bfloat16(__expf(fminf(sc, 60.0f)));
        } else if (MODE == 2) {
          Cb[off] = __float2bfloat16(v);     // unnormalized ctx'
        } else if (MODE == 3) {
          Cf[off] = v * inv_sum[row] + biasz[col] + xres[off];
        } else {                             // MODE 4: bias by ROW (= h index)
          Cb[off] = __float2bfloat16(v + bias0[row]);
        }
      }
    }
  }
}

// ---- rownorm core: sum E row, write inv_sum + normalized fp32 attn
__device__ __forceinline__ void rownorm_core(float* red, long row, const bf16* E,
                                             float* attn_f, float* inv_sum) {
  const int tid = threadIdx.x;
  const uint4 d = *(const uint4*)(E + row * (long)S_ + tid * 8);
  float ev[8];
  ev[0] = __uint_as_float(d.x << 16); ev[1] = __uint_as_float(d.x & 0xffff0000u);
  ev[2] = __uint_as_float(d.y << 16); ev[3] = __uint_as_float(d.y & 0xffff0000u);
  ev[4] = __uint_as_float(d.z << 16); ev[5] = __uint_as_float(d.z & 0xffff0000u);
  ev[6] = __uint_as_float(d.w << 16); ev[7] = __uint_as_float(d.w & 0xffff0000u);
  float s = 0.f;
#pragma unroll
  for (int i = 0; i < 8; ++i) s += ev[i];
  s = wave_reduce_sum(s);
  if ((tid & 63) == 0) red[tid >> 6] = s;
  __syncthreads();
  const float inv = 1.0f / fmaxf(red[0] + red[1] + red[2] + red[3], 1e-30f);
  if (tid == 0) inv_sum[row] = inv;
  float4 o0, o1;
  o0.x = bf16r(ev[0] * inv); o0.y = bf16r(ev[1] * inv);
  o0.z = bf16r(ev[2] * inv); o0.w = bf16r(ev[3] * inv);
  o1.x = bf16r(ev[4] * inv); o1.y = bf16r(ev[5] * inv);
  o1.z = bf16r(ev[6] * inv); o1.w = bf16r(ev[7] * inv);
  float4* dst = (float4*)(attn_f + row * (long)S_ + tid * 8);
  dst[0] = o0;
  dst[1] = o1;
}

// ================= kernels ======================================================

__global__ void prep_kernel(const float* __restrict__ Wq, const float* __restrict__ Wk,
                            const float* __restrict__ Wv, const float* __restrict__ Wo,
                            bf16* __restrict__ wdst,
                            const float* __restrict__ x, bf16* __restrict__ xpb,
                            const int* __restrict__ mask, unsigned* __restrict__ mask_bits,
                            const float* __restrict__ pos_bias, bf16* __restrict__ pbb) {
  prep_core(blockIdx.x, Wq, Wk, Wv, Wo, wdst, x, xpb, mask, mask_bits, pos_bias, pbb);
}

// Merged q,k projection (vblocks 0..1023 = 64x8x2) + vT (1024..1535 = 8x16x4).
__global__ void qkvt_kernel(const bf16* __restrict__ xpb, const bf16* __restrict__ wts,
                            bf16* __restrict__ q_b, bf16* __restrict__ vT,
                            const float* __restrict__ bq, const float* __restrict__ bk,
                            const float* __restrict__ bv) {
  __shared__ bf16 As[128 * 64];
  __shared__ bf16 Bs[128 * 64];
  const int vb = blockIdx.x;
  if (vb < 1024) {
    const int bx = vb & 63, by = (vb >> 6) & 7, z = vb >> 9;
    gemm_core<0, false>(As, Bs, bx, by, z, xpb, 0, wts, HH,
                        q_b, nullptr, BSH, B_ * S_, H_, H_,
                        bq, bk, nullptr, nullptr, nullptr, nullptr);
  } else {
    const int w = vb - 1024, bx = w & 7, by = (w >> 3) & 15, z = w >> 7;
    gemm_core<4, false>(As, Bs, bx, by, z, wts + 2 * HH, 0, xpb, SH,
                        vT, nullptr, SH, H_, S_, H_,
                        bv, nullptr, nullptr, nullptr, nullptr, nullptr);
  }
}

// Merged ctx' = E@v (vblocks 0..511, UNNORMALIZED) + rownorm (512..8703).
// Independent after deferring inv_sum to MODE 3's epilogue: rownorm needs only
// MODE 1's E; ctx' needs E + vT. BW-bound rownorm blocks backfill CUs as the
// compute-bound GEMM blocks drain — hides rownorm and kills one dispatch gap.
__global__ void ctxnorm_kernel(const bf16* __restrict__ attn_b, const bf16* __restrict__ vT,
                               bf16* __restrict__ ctx, float* __restrict__ attn_f,
                               float* __restrict__ inv_sum) {
  __shared__ bf16  As[128 * 64];
  __shared__ bf16  Bs[128 * 64];
  __shared__ float red[4];
  const int vb = blockIdx.x;
  if (vb < 512) {
    const int bx = vb & 15, by = (vb >> 4) & 7, z = vb >> 7;
    gemm_core<2, false>(As, Bs, bx, by, z, attn_b, SS, vT, SH,
                        ctx, nullptr, SH, S_, H_, S_,
                        nullptr, nullptr, nullptr, nullptr, nullptr, nullptr);
  } else {
    rownorm_core(red, vb - 512, attn_b, attn_f, inv_sum);
  }
}

template <int MODE, bool DBUF>
__global__ void gemm_nt(const bf16* __restrict__ A, long sA,
                        const bf16* __restrict__ Bm, long sB,
                        bf16* __restrict__ Cb, float* __restrict__ Cf, long sC,
                        int M, int N, int K,
                        const float* __restrict__ bias0,
                        const float* __restrict__ bias1,
                        const bf16* __restrict__ pbb,
                        const unsigned* __restrict__ mask_bits,
                        const float* __restrict__ xres,
                        const float* __restrict__ inv_sum) {
  constexpr int NBUF = DBUF ? 2 : 1;
  __shared__ bf16 As[NBUF * 128 * 64];
  __shared__ bf16 Bs[NBUF * 128 * 64];
  gemm_core<MODE, DBUF>(As, Bs, blockIdx.x, blockIdx.y, blockIdx.z,
                        A, sA, Bm, sB, Cb, Cf, sC, M, N, K,
                        bias0, bias1, pbb, mask_bits, xres, inv_sum);
}

__global__ void ln_kernel(float* __restrict__ h, const float* __restrict__ gamma,
                          const float* __restrict__ beta) {
  const long row = blockIdx.x;
  float* hr = h + row * (long)H_;
  const int tid = threadIdx.x;
  const float4 v4 = ((const float4*)hr)[tid];
  float s = v4.x + v4.y + v4.z + v4.w;
  s = wave_reduce_sum(s);
  __shared__ float redA[4], redB[4];
  if ((tid & 63) == 0) redA[tid >> 6] = s;
  __syncthreads();
  const float mu = (redA[0] + redA[1] + redA[2] + redA[3]) * (1.0f / H_);
  const float dx = v4.x - mu, dy = v4.y - mu, dz = v4.z - mu, dw = v4.w - mu;
  float vs = dx * dx + dy * dy + dz * dz + dw * dw;
  vs = wave_reduce_sum(vs);
  if ((tid & 63) == 0) redB[tid >> 6] = vs;
  __syncthreads();
  const float var  = (redB[0] + redB[1] + redB[2] + redB[3]) * (1.0f / H_);
  const float rstd = rsqrtf(var + 1e-5f);
  const float4 g4 = ((const float4*)gamma)[tid];
  const float4 b4 = ((const float4*)beta)[tid];
  float4 o;
  o.x = bf16r(dx * rstd * g4.x + b4.x);
  o.y = bf16r(dy * rstd * g4.y + b4.y);
  o.z = bf16r(dz * rstd * g4.z + b4.z);
  o.w = bf16r(dw * rstd * g4.w + b4.w);
  ((float4*)hr)[tid] = o;
}

extern "C" void kernel_launch(void* const* d_in, const int* in_sizes, int n_in,
                              void* d_out, int out_size, void* d_ws, size_t ws_size,
                              hipStream_t stream) {
  const float* x        = (const float*)d_in[0];
  const int*   mask     = (const int*)d_in[1];
  const float* Wq       = (const float*)d_in[2];
  const float* bq       = (const float*)d_in[3];
  const float* Wk       = (const float*)d_in[4];
  const float* bk       = (const float*)d_in[5];
  const float* Wv       = (const float*)d_in[6];
  const float* bv       = (const float*)d_in[7];
  const float* pos_bias = (const float*)d_in[8];
  const float* Wo       = (const float*)d_in[9];
  const float* bo       = (const float*)d_in[10];
  const float* gamma    = (const float*)d_in[11];
  const float* beta     = (const float*)d_in[12];

  // fp32 outputs: normed [0,32MiB), attn [32,96MiB)
  float* normed_f = (float*)d_out;
  float* attn_f   = (float*)((char*)d_out + ((size_t)32 << 20));

  const size_t MiB = (size_t)1 << 20;
  bf16*     xpb       = (bf16*)d_ws;                          // [  0, 16)
  bf16*     q_b       = (bf16*)((char*)d_ws +  16 * MiB);     // [ 16, 32)
  bf16*     kbuf      = (bf16*)((char*)d_ws +  32 * MiB);     // [ 32, 48)
  bf16*     vT        = (bf16*)((char*)d_ws +  64 * MiB);     // [ 64, 80)
  bf16*     ctx       = (bf16*)((char*)d_ws +  80 * MiB);     // [ 80, 96)
  bf16*     attn_b    = (bf16*)((char*)d_ws +  96 * MiB);     // [ 96,128)
  bf16*     wts       = (bf16*)((char*)d_ws + 128 * MiB);     // [128,136)
  float*    inv_sum   = (float*)((char*)d_ws + 136 * MiB);    // 32 KB
  unsigned* mask_bits = (unsigned*)((char*)d_ws + 137 * MiB); // 2 MiB
  bf16*     pbb       = (bf16*)((char*)d_ws + 139 * MiB);     // 8 MiB
  bf16* Wob = wts + 3 * HH;

  const int MQKV = B_ * S_;   // 8192

  // 1) prep: weights (4096) + xpb (16384) + mask bits (2048) + pos_bias bf16 (4096)
  prep_kernel<<<dim3(26624), 256, 0, stream>>>(Wq, Wk, Wv, Wo, wts, x, xpb,
                                               mask, mask_bits, pos_bias, pbb);

  // 2) q,k proj + vT in ONE dispatch
  qkvt_kernel<<<dim3(1536), 256, 0, stream>>>(xpb, wts, q_b, vT, bq, bk, bv);

  // 3) E = exp((q/32)*k^T + pbb, masked) -> bf16 (single-buffer — measured best)
  gemm_nt<1, false><<<dim3(16, 16, B_), 256, 0, stream>>>(q_b, SH, kbuf, SH,
                                                          attn_b, nullptr, SS,
                                                          S_, S_, H_, nullptr, nullptr,
                                                          pbb, mask_bits, nullptr, nullptr);

  // 4) ctx' = E@v (unnormalized) + rownorm in ONE dispatch (independent work)
  ctxnorm_kernel<<<dim3(512 + B_ * S_), 256, 0, stream>>>(attn_b, vT, ctx,
                                                          attn_f, inv_sum);

  // 5) h = inv_sum[row]*(ctx' Wo^T) + bo + x (normalization applied here)
  gemm_nt<3, false><<<dim3(64, 8, 1), 256, 0, stream>>>(ctx, 0, Wob, 0, nullptr, normed_f, 0,
                                                        MQKV, H_, H_, bo, nullptr,
                                                        nullptr, nullptr, x, inv_sum);

  // 6) layernorm in-place (row-local)
  ln_kernel<<<B_ * S_, 256, 0, stream>>>(normed_f, gamma, beta);
}

// Round 15
// 390.704 us; speedup vs baseline: 3.0913x; 1.0081x over previous
//
#include <hip/hip_runtime.h>
#include <hip/hip_bf16.h>
#include <math.h>

typedef __hip_bfloat16 bf16;
typedef __bf16 bf16x8 __attribute__((ext_vector_type(8)));
typedef float f32x4 __attribute__((ext_vector_type(4)));

static constexpr int  B_  = 4, S_ = 2048, H_ = 1024;
static constexpr long BSH = (long)B_ * S_ * H_;   // 8,388,608
static constexpr long SH  = (long)S_ * H_;        // 2,097,152
static constexpr long SS  = (long)S_ * S_;        // 4,194,304
static constexpr long HH  = (long)H_ * H_;        // 1,048,576

// async global->LDS, 16B per lane; LDS dest is wave-uniform base + lane*16
#define GLOAD_LDS16(gp, lp)                                                          \
  __builtin_amdgcn_global_load_lds((__attribute__((address_space(1))) void*)(gp),    \
                                   (__attribute__((address_space(3))) void*)(lp),    \
                                   16, 0, 0)

// raw barrier (does NOT drain vmcnt) + compiler memory fence
#define BARRIER() do { __builtin_amdgcn_s_barrier(); asm volatile("" ::: "memory"); } while (0)

template <int N> __device__ __forceinline__ void waitcnt_vm() {
  if constexpr (N == 0)      asm volatile("s_waitcnt vmcnt(0)" ::: "memory");
  else if constexpr (N == 8) asm volatile("s_waitcnt vmcnt(8)" ::: "memory");
}

__device__ __forceinline__ float wave_reduce_sum(float v) {
#pragma unroll
  for (int o = 32; o; o >>= 1) v += __shfl_xor(v, o, 64);
  return v;
}
__device__ __forceinline__ float bf16r(float v) {
  return __bfloat162float(__float2bfloat16(v));
}
// T1 XCD swizzle: bijective for nwg = 8*chunk; gives each XCD a contiguous
// work chunk (default dispatch round-robins bid%8 across XCDs).
__device__ __forceinline__ int xcd_swz(int bid, int chunk) {
  return (bid & 7) * chunk + (bid >> 3);
}

// ================= device cores =================================================

// ---- prep virtual-block: weights (0..4095) + PE-add (4096..20479)
//      + mask bit-pack (20480..22527) + pos_bias->bf16 (22528..26623)
__device__ __forceinline__ void prep_core(
    int bx, const float* Wq, const float* Wk, const float* Wv, const float* Wo,
    bf16* wdst, const float* x, bf16* xpb,
    const int* mask, unsigned* mask_bits, const float* pos_bias, bf16* pbb) {
  const int tid = threadIdx.x;
  if (bx < 4096) {
    const int w = bx >> 10;
    const float* src = (w == 0) ? Wq : (w == 1) ? Wk : (w == 2) ? Wv : Wo;
    bf16* d = wdst + (long)w * HH;
    const int idx = ((bx & 1023) << 8) + tid;
    const float4 f = ((const float4*)src)[idx];
    d[idx * 4 + 0] = __float2bfloat16(f.x);
    d[idx * 4 + 1] = __float2bfloat16(f.y);
    d[idx * 4 + 2] = __float2bfloat16(f.z);
    d[idx * 4 + 3] = __float2bfloat16(f.w);
  } else if (bx < 20480) {
    const long idx = (((long)(bx - 4096)) << 8) + tid;     // over B*S*(H/2)
    const int  i   = (int)(idx & (H_ / 2 - 1));
    const long bs  = idx >> 9;
    const int  s   = (int)(bs & (S_ - 1));
    const float div = __expf((float)(2 * i) * (-9.210340371976184f / (float)H_));
    const float ang = (float)s * div;
    const float2 xv = ((const float2*)x)[idx];
    xpb[idx * 2 + 0] = __float2bfloat16(xv.x + __sinf(ang));
    xpb[idx * 2 + 1] = __float2bfloat16(xv.y + __cosf(ang));
  } else if (bx < 22528) {
    const long uidx = (((long)(bx - 20480)) << 8) + tid;
    const int4* mp  = (const int4*)mask + uidx * 8;
    unsigned bits = 0;
#pragma unroll
    for (int q = 0; q < 8; ++q) {
      const int4 v = mp[q];
      bits |= (v.x ? 1u : 0u) << (q * 4 + 0);
      bits |= (v.y ? 1u : 0u) << (q * 4 + 1);
      bits |= (v.z ? 1u : 0u) << (q * 4 + 2);
      bits |= (v.w ? 1u : 0u) << (q * 4 + 3);
    }
    mask_bits[uidx] = bits;
  } else {
    const long idx = (((long)(bx - 22528)) << 8) + tid;
    const float4 f = ((const float4*)pos_bias)[idx];
    bf16* d = pbb + idx * 4;
    d[0] = __float2bfloat16(f.x);
    d[1] = __float2bfloat16(f.y);
    d[2] = __float2bfloat16(f.z);
    d[3] = __float2bfloat16(f.w);
  }
}

// ---- NT GEMM core, 128x128 tile, BK=64, 256 thr. As/Bs point to NBUF x 16KB.
// DBUF=false: stage -> syncthreads(drain) -> compute -> syncthreads (r6 winner).
// Read-side k-slot XOR (row&7) swizzle; inverse perm on GLOBAL source (rule 21;
// conflicts measured 0).
// MODE 0: Cb = bf16(acc + biasz[col]); z==0 scaled 1/32 (exact exponent shift)
// MODE 1: Cb = bf16(exp(clamp(acc + pbb, maskbit)))   (acc pre-scaled)
// MODE 2: Cb = bf16(acc)  — UNNORMALIZED ctx' = E@v (inv_sum deferred to MODE 3)
// MODE 3: Cf = inv_sum[row]*acc + bias0[col] + xres[m,n]  (fp32)
// MODE 4: Cb = bf16(acc + bias0[ROW])        (vT = Wv @ xpb^T + bv, H x S out)
template <int MODE, bool DBUF>
__device__ __forceinline__ void gemm_core(
    bf16* As, bf16* Bs, int bxx, int byy, int z,
    const bf16* A, long sA, const bf16* Bm, long sB,
    bf16* Cb, float* Cf, long sC, int M, int N, int K,
    const float* bias0, const float* bias1,
    const bf16* pbb, const unsigned* mask_bits,
    const float* xres, const float* inv_sum) {
  constexpr int BM = 128, BN = 128, BK = 64;
  constexpr int TILE = BM * BK;              // 8192 bf16 = 16KB

  const int tid  = threadIdx.x;
  const int lane = tid & 63;
  const int wave = tid >> 6;
  const int wm   = wave & 1;
  const int wn   = wave >> 1;
  const int m0   = bxx * BM;
  const int n0   = byy * BN;

  const bf16* Ab = A  + (long)z * sA;
  const bf16* Bb = Bm + (long)z * sB;

  const int rw = tid >> 3;                   // base row (rows rw+32q)
  const int cp = (tid & 7) ^ (rw & 7);       // permuted global 16B-colslot
  const bf16* ga = Ab + (long)(m0 + rw) * K + cp * 8;
  const bf16* gb = Bb + (long)(n0 + rw) * K + cp * 8;

  auto stage = [&](int tile, int buf) {
    const long k0 = (long)tile * BK;
#pragma unroll
    for (int q = 0; q < 4; ++q) {
      GLOAD_LDS16(ga + (long)(32 * q) * K + k0, As + buf * TILE + tid * 8 + q * 2048);
      GLOAD_LDS16(gb + (long)(32 * q) * K + k0, Bs + buf * TILE + tid * 8 + q * 2048);
    }
  };

  f32x4 acc[4][4] = {};

  const int fr     = lane & 15;
  const int k0slot = lane >> 4;
  const int sw     = fr & 7;

  auto tile_compute = [&](const char* bAc, const char* bBc) {
#pragma unroll
    for (int ks = 0; ks < 2; ++ks) {
      const int co = ((k0slot + 4 * ks) ^ sw) << 4;
      bf16x8 af[4], bfv[4];
#pragma unroll
      for (int i = 0; i < 4; ++i) {
        af[i]  = *(const bf16x8*)(bAc + (wm * 64 + i * 16 + fr) * 128 + co);
        bfv[i] = *(const bf16x8*)(bBc + (wn * 64 + i * 16 + fr) * 128 + co);
      }
#pragma unroll
      for (int i = 0; i < 4; ++i)
#pragma unroll
        for (int j = 0; j < 4; ++j)
          acc[i][j] = __builtin_amdgcn_mfma_f32_16x16x32_bf16(af[i], bfv[j], acc[i][j], 0, 0, 0);
    }
  };

  const int nkt = K / BK;
  if constexpr (DBUF) {
    stage(0, 0);
    for (int kt = 0; kt < nkt; ++kt) {
      const int cur = kt & 1;
      if (kt + 1 < nkt) {
        stage(kt + 1, cur ^ 1);
        waitcnt_vm<8>();
      } else {
        waitcnt_vm<0>();
      }
      BARRIER();
      tile_compute((const char*)(As + cur * TILE), (const char*)(Bs + cur * TILE));
      BARRIER();
    }
  } else {
    for (int kt = 0; kt < nkt; ++kt) {
      stage(kt, 0);
      __syncthreads();
      tile_compute((const char*)As, (const char*)Bs);
      __syncthreads();
    }
  }

  const float* biasz = (MODE == 0) ? ((z == 0) ? bias0 : bias1) : bias0;
  const int cc = lane & 15;
  const int cr = (lane >> 4) * 4;
#pragma unroll
  for (int i = 0; i < 4; ++i) {
    const int rowb = m0 + wm * 64 + i * 16 + cr;
#pragma unroll
    for (int j = 0; j < 4; ++j) {
      const int col = n0 + wn * 64 + j * 16 + cc;
#pragma unroll
      for (int r = 0; r < 4; ++r) {
        const int  row  = rowb + r;
        const long loff = (long)row * N + col;
        const long off  = (long)z * sC + loff;
        const float v   = acc[i][j][r];
        if (MODE == 0) {
          float o = v + biasz[col];
          if (z == 0) o *= 0.03125f;         // pre-scale q by 1/32 (exact)
          Cb[off] = __float2bfloat16(o);
        } else if (MODE == 1) {
          const unsigned mw = mask_bits[off >> 5];
          float sc = v + __bfloat162float(pbb[loff]);
          if (((mw >> (col & 31)) & 1u) == 0u) sc = -1e9f;
          Cb[off] = __float2bfloat16(__expf(fminf(sc, 60.0f)));
        } else if (MODE == 2) {
          Cb[off] = __float2bfloat16(v);     // unnormalized ctx'
        } else if (MODE == 3) {
          Cf[off] = v * inv_sum[row] + biasz[col] + xres[off];
        } else {                             // MODE 4: bias by ROW (= h index)
          Cb[off] = __float2bfloat16(v + bias0[row]);
        }
      }
    }
  }
}

// ---- rownorm core: sum E row, write inv_sum + normalized fp32 attn
__device__ __forceinline__ void rownorm_core(float* red, long row, const bf16* E,
                                             float* attn_f, float* inv_sum) {
  const int tid = threadIdx.x;
  const uint4 d = *(const uint4*)(E + row * (long)S_ + tid * 8);
  float ev[8];
  ev[0] = __uint_as_float(d.x << 16); ev[1] = __uint_as_float(d.x & 0xffff0000u);
  ev[2] = __uint_as_float(d.y << 16); ev[3] = __uint_as_float(d.y & 0xffff0000u);
  ev[4] = __uint_as_float(d.z << 16); ev[5] = __uint_as_float(d.z & 0xffff0000u);
  ev[6] = __uint_as_float(d.w << 16); ev[7] = __uint_as_float(d.w & 0xffff0000u);
  float s = 0.f;
#pragma unroll
  for (int i = 0; i < 8; ++i) s += ev[i];
  s = wave_reduce_sum(s);
  if ((tid & 63) == 0) red[tid >> 6] = s;
  __syncthreads();
  const float inv = 1.0f / fmaxf(red[0] + red[1] + red[2] + red[3], 1e-30f);
  if (tid == 0) inv_sum[row] = inv;
  float4 o0, o1;
  o0.x = bf16r(ev[0] * inv); o0.y = bf16r(ev[1] * inv);
  o0.z = bf16r(ev[2] * inv); o0.w = bf16r(ev[3] * inv);
  o1.x = bf16r(ev[4] * inv); o1.y = bf16r(ev[5] * inv);
  o1.z = bf16r(ev[6] * inv); o1.w = bf16r(ev[7] * inv);
  float4* dst = (float4*)(attn_f + row * (long)S_ + tid * 8);
  dst[0] = o0;
  dst[1] = o1;
}

// ================= kernels ======================================================

__global__ void prep_kernel(const float* __restrict__ Wq, const float* __restrict__ Wk,
                            const float* __restrict__ Wv, const float* __restrict__ Wo,
                            bf16* __restrict__ wdst,
                            const float* __restrict__ x, bf16* __restrict__ xpb,
                            const int* __restrict__ mask, unsigned* __restrict__ mask_bits,
                            const float* __restrict__ pos_bias, bf16* __restrict__ pbb) {
  prep_core(blockIdx.x, Wq, Wk, Wv, Wo, wdst, x, xpb, mask, mask_bits, pos_bias, pbb);
}

// Merged q,k projection (works 0..1023 = 64x8x2) + vT (1024..1535 = 8x16x4),
// each sub-range XCD-swizzled so one XCD's blocks share weight/xpb panels.
__global__ void qkvt_kernel(const bf16* __restrict__ xpb, const bf16* __restrict__ wts,
                            bf16* __restrict__ q_b, bf16* __restrict__ vT,
                            const float* __restrict__ bq, const float* __restrict__ bk,
                            const float* __restrict__ bv) {
  __shared__ bf16 As[128 * 64];
  __shared__ bf16 Bs[128 * 64];
  const int bid = blockIdx.x;
  if (bid < 1024) {
    const int vb = xcd_swz(bid, 128);        // XCD chunk: z fixed, by span 2
    const int bx = vb & 63, by = (vb >> 6) & 7, z = vb >> 9;
    gemm_core<0, false>(As, Bs, bx, by, z, xpb, 0, wts, HH,
                        q_b, nullptr, BSH, B_ * S_, H_, H_,
                        bq, bk, nullptr, nullptr, nullptr, nullptr);
  } else {
    const int w = xcd_swz(bid - 1024, 64);   // XCD chunk shares xpb panels
    const int bx = w & 7, by = (w >> 3) & 15, z = w >> 7;
    gemm_core<4, false>(As, Bs, bx, by, z, wts + 2 * HH, 0, xpb, SH,
                        vT, nullptr, SH, H_, S_, H_,
                        bv, nullptr, nullptr, nullptr, nullptr, nullptr);
  }
}

// E = exp((q/32)k^T + pbb, masked), 1024 blocks XCD-swizzled (XCD chunk = half a
// batch slice: 16 q panels + 8 k panels mostly L2-resident).
__global__ void e_kernel(const bf16* __restrict__ q_b, const bf16* __restrict__ kbuf,
                         bf16* __restrict__ attn_b, const bf16* __restrict__ pbb,
                         const unsigned* __restrict__ mask_bits) {
  __shared__ bf16 As[128 * 64];
  __shared__ bf16 Bs[128 * 64];
  const int vb = xcd_swz(blockIdx.x, 128);
  const int bx = vb & 15, by = (vb >> 4) & 15, z = vb >> 8;
  gemm_core<1, false>(As, Bs, bx, by, z, q_b, SH, kbuf, SH,
                      attn_b, nullptr, SS, S_, S_, H_,
                      nullptr, nullptr, pbb, mask_bits, nullptr, nullptr);
}

// Merged ctx' = E@v (works 0..511, UNNORMALIZED, XCD-swizzled within range) +
// rownorm (512..8703, unswizzled). NOTE: swizzle must stay WITHIN the GEMM
// range — swizzling across the boundary would pin all GEMM blocks to XCD 0.
__global__ void ctxnorm_kernel(const bf16* __restrict__ attn_b, const bf16* __restrict__ vT,
                               bf16* __restrict__ ctx, float* __restrict__ attn_f,
                               float* __restrict__ inv_sum) {
  __shared__ bf16  As[128 * 64];
  __shared__ bf16  Bs[128 * 64];
  __shared__ float red[4];
  const int bid = blockIdx.x;
  if (bid < 512) {
    const int vb = xcd_swz(bid, 64);         // XCD chunk shares vT/E panels
    const int bx = vb & 15, by = (vb >> 4) & 7, z = vb >> 7;
    gemm_core<2, false>(As, Bs, bx, by, z, attn_b, SS, vT, SH,
                        ctx, nullptr, SH, S_, H_, S_,
                        nullptr, nullptr, nullptr, nullptr, nullptr, nullptr);
  } else {
    rownorm_core(red, bid - 512, attn_b, attn_f, inv_sum);
  }
}

// h = inv_sum[row]*(ctx' Wo^T) + bo + x, 512 blocks XCD-swizzled (XCD chunk =
// one Wo panel shared by 64 blocks).
__global__ void oproj_kernel(const bf16* __restrict__ ctx, const bf16* __restrict__ Wob,
                             float* __restrict__ normed_f, const float* __restrict__ bo,
                             const float* __restrict__ x, const float* __restrict__ inv_sum) {
  __shared__ bf16 As[128 * 64];
  __shared__ bf16 Bs[128 * 64];
  const int vb = xcd_swz(blockIdx.x, 64);
  const int bx = vb & 63, by = vb >> 6;
  gemm_core<3, false>(As, Bs, bx, by, 0, ctx, 0, Wob, 0,
                      nullptr, normed_f, 0, B_ * S_, H_, H_,
                      bo, nullptr, nullptr, nullptr, x, inv_sum);
}

__global__ void ln_kernel(float* __restrict__ h, const float* __restrict__ gamma,
                          const float* __restrict__ beta) {
  const long row = blockIdx.x;
  float* hr = h + row * (long)H_;
  const int tid = threadIdx.x;
  const float4 v4 = ((const float4*)hr)[tid];
  float s = v4.x + v4.y + v4.z + v4.w;
  s = wave_reduce_sum(s);
  __shared__ float redA[4], redB[4];
  if ((tid & 63) == 0) redA[tid >> 6] = s;
  __syncthreads();
  const float mu = (redA[0] + redA[1] + redA[2] + redA[3]) * (1.0f / H_);
  const float dx = v4.x - mu, dy = v4.y - mu, dz = v4.z - mu, dw = v4.w - mu;
  float vs = dx * dx + dy * dy + dz * dz + dw * dw;
  vs = wave_reduce_sum(vs);
  if ((tid & 63) == 0) redB[tid >> 6] = vs;
  __syncthreads();
  const float var  = (redB[0] + redB[1] + redB[2] + redB[3]) * (1.0f / H_);
  const float rstd = rsqrtf(var + 1e-5f);
  const float4 g4 = ((const float4*)gamma)[tid];
  const float4 b4 = ((const float4*)beta)[tid];
  float4 o;
  o.x = bf16r(dx * rstd * g4.x + b4.x);
  o.y = bf16r(dy * rstd * g4.y + b4.y);
  o.z = bf16r(dz * rstd * g4.z + b4.z);
  o.w = bf16r(dw * rstd * g4.w + b4.w);
  ((float4*)hr)[tid] = o;
}

extern "C" void kernel_launch(void* const* d_in, const int* in_sizes, int n_in,
                              void* d_out, int out_size, void* d_ws, size_t ws_size,
                              hipStream_t stream) {
  const float* x        = (const float*)d_in[0];
  const int*   mask     = (const int*)d_in[1];
  const float* Wq       = (const float*)d_in[2];
  const float* bq       = (const float*)d_in[3];
  const float* Wk       = (const float*)d_in[4];
  const float* bk       = (const float*)d_in[5];
  const float* Wv       = (const float*)d_in[6];
  const float* bv       = (const float*)d_in[7];
  const float* pos_bias = (const float*)d_in[8];
  const float* Wo       = (const float*)d_in[9];
  const float* bo       = (const float*)d_in[10];
  const float* gamma    = (const float*)d_in[11];
  const float* beta     = (const float*)d_in[12];

  // fp32 outputs: normed [0,32MiB), attn [32,96MiB)
  float* normed_f = (float*)d_out;
  float* attn_f   = (float*)((char*)d_out + ((size_t)32 << 20));

  const size_t MiB = (size_t)1 << 20;
  bf16*     xpb       = (bf16*)d_ws;                          // [  0, 16)
  bf16*     q_b       = (bf16*)((char*)d_ws +  16 * MiB);     // [ 16, 32)
  bf16*     kbuf      = (bf16*)((char*)d_ws +  32 * MiB);     // [ 32, 48)
  bf16*     vT        = (bf16*)((char*)d_ws +  64 * MiB);     // [ 64, 80)
  bf16*     ctx       = (bf16*)((char*)d_ws +  80 * MiB);     // [ 80, 96)
  bf16*     attn_b    = (bf16*)((char*)d_ws +  96 * MiB);     // [ 96,128)
  bf16*     wts       = (bf16*)((char*)d_ws + 128 * MiB);     // [128,136)
  float*    inv_sum   = (float*)((char*)d_ws + 136 * MiB);    // 32 KB
  unsigned* mask_bits = (unsigned*)((char*)d_ws + 137 * MiB); // 2 MiB
  bf16*     pbb       = (bf16*)((char*)d_ws + 139 * MiB);     // 8 MiB
  bf16* Wob = wts + 3 * HH;

  // 1) prep: weights (4096) + xpb (16384) + mask bits (2048) + pos_bias bf16 (4096)
  prep_kernel<<<dim3(26624), 256, 0, stream>>>(Wq, Wk, Wv, Wo, wts, x, xpb,
                                               mask, mask_bits, pos_bias, pbb);

  // 2) q,k proj + vT in ONE dispatch (XCD-swizzled)
  qkvt_kernel<<<dim3(1536), 256, 0, stream>>>(xpb, wts, q_b, vT, bq, bk, bv);

  // 3) E = exp((q/32)*k^T + pbb, masked) (XCD-swizzled)
  e_kernel<<<dim3(1024), 256, 0, stream>>>(q_b, kbuf, attn_b, pbb, mask_bits);

  // 4) ctx' = E@v (unnormalized, XCD-swizzled) + rownorm in ONE dispatch
  ctxnorm_kernel<<<dim3(512 + B_ * S_), 256, 0, stream>>>(attn_b, vT, ctx,
                                                          attn_f, inv_sum);

  // 5) h = inv_sum[row]*(ctx' Wo^T) + bo + x (XCD-swizzled)
  oproj_kernel<<<dim3(512), 256, 0, stream>>>(ctx, Wob, normed_f, bo, x, inv_sum);

  // 6) layernorm in-place (row-local)
  ln_kernel<<<B_ * S_, 256, 0, stream>>>(normed_f, gamma, beta);
}